// Round 5
// baseline (106.596 us; speedup 1.0000x reference)
//
#include <hip/hip_runtime.h>

// ChamferLoss: B=4, N=M=8192, D=3, fp32.
// loss = mean_b[ mean(pred2gt) + mean(gt2pred) + max(pred2gt) ]
// R5: packed-fp32 (v_pk_fma_f32, gfx90a+/gfx950 VOP3P). Issue rate stuck at
// ~54% of VALU wave-inst ceiling across R2-R4 regardless of occupancy/ILP ->
// halve the instruction count instead: register tile = float2 point-pairs,
// 6 pk_fma + 2 min3 per (2y x 2pts) = 2.0 instr/pair (was 3.5).
// atomicMin-fused combine (uint order == float order for nonneg), 3 nodes.

typedef float v2f __attribute__((ext_vector_type(2)));

#define BATCH   4
#define NPTS    8192
#define SLICES  64
#define MS      (NPTS / SLICES)     // 128 y-points per slice
#define NP2     8                   // point-PAIRS per thread (16 points)
#define TPB     256
#define CHUNK   (TPB * NP2 * 2)     // 4096 x-points per block
#define NCHUNKS (NPTS / CHUNK)      // 2

__global__ __launch_bounds__(TPB, 4)   // cap VGPR <=128: 4 waves/SIMD
void nn_fused(const float* __restrict__ pred,
              const float* __restrict__ gt,
              unsigned int* __restrict__ pmin) {
    const int c  = blockIdx.x;       // x chunk
    const int s  = blockIdx.y;       // y slice
    const int bd = blockIdx.z;       // b*2 + dir
    const int b  = bd >> 1;
    const int dir = bd & 1;
    const float* x = (dir ? gt : pred) + (size_t)b * NPTS * 3;
    const float* y = (dir ? pred : gt) + (size_t)b * NPTS * 3;

    __shared__ float4 ys[MS];        // {yx, yy, yz, y2}  (2 KB)
    const int t = threadIdx.x;
    if (t < MS) {
        const float yx = y[(s * MS + t) * 3 + 0];
        const float yy = y[(s * MS + t) * 3 + 1];
        const float yz = y[(s * MS + t) * 3 + 2];
        ys[t] = make_float4(yx, yy, yz, yx * yx + yy * yy + yz * yz);
    }
    __syncthreads();

    // Per point: e_j = y2 + (-2x).y ; d = x2 + min_j e_j  (x2 hoisted).
    // Two points per v2f lane-pair.
    v2f px[NP2], py[NP2], pz[NP2], x2[NP2], emin[NP2];
    #pragma unroll
    for (int k = 0; k < NP2; ++k) {
        const int p0 = c * CHUNK + (k * TPB + t) * 2;   // point pair p0, p0+1
        const float ax = x[p0 * 3 + 0], ay = x[p0 * 3 + 1], az = x[p0 * 3 + 2];
        const float bx = x[p0 * 3 + 3], by = x[p0 * 3 + 4], bz = x[p0 * 3 + 5];
        x2[k] = (v2f){ax * ax + ay * ay + az * az, bx * bx + by * by + bz * bz};
        px[k] = (v2f){-2.f * ax, -2.f * bx};
        py[k] = (v2f){-2.f * ay, -2.f * by};
        pz[k] = (v2f){-2.f * az, -2.f * bz};
        emin[k] = (v2f){3.4e38f, 3.4e38f};
    }

    for (int j = 0; j < MS; j += 2) {
        const float4 q0 = ys[j];
        const float4 q1 = ys[j + 1];
        const v2f q0x = {q0.x, q0.x}, q0y = {q0.y, q0.y}, q0z = {q0.z, q0.z}, q0w = {q0.w, q0.w};
        const v2f q1x = {q1.x, q1.x}, q1y = {q1.y, q1.y}, q1z = {q1.z, q1.z}, q1w = {q1.w, q1.w};
        #pragma unroll
        for (int k = 0; k < NP2; ++k) {
            v2f e0 = __builtin_elementwise_fma(pz[k], q0z,
                     __builtin_elementwise_fma(py[k], q0y,
                     __builtin_elementwise_fma(px[k], q0x, q0w)));
            v2f e1 = __builtin_elementwise_fma(pz[k], q1z,
                     __builtin_elementwise_fma(py[k], q1y,
                     __builtin_elementwise_fma(px[k], q1x, q1w)));
            emin[k] = __builtin_elementwise_min(emin[k],
                      __builtin_elementwise_min(e0, e1));   // 2x v_min3_f32
        }
    }

    unsigned int* o = pmin + (size_t)bd * NPTS + c * CHUNK;
    #pragma unroll
    for (int k = 0; k < NP2; ++k) {
        v2f d = emin[k] + x2[k];
        d = __builtin_elementwise_max(d, (v2f){0.f, 0.f});   // sqdist >= 0
        const int i0 = (k * TPB + t) * 2;
        atomicMin(&o[i0 + 0], __float_as_uint(d.x));
        atomicMin(&o[i0 + 1], __float_as_uint(d.y));
    }
}

// One 1024-thread block: 128 threads per bd; sum + max per bd; write out[0].
__global__ __launch_bounds__(1024)
void reduce_all(const unsigned int* __restrict__ pmin,
                float* __restrict__ out) {
    const int t  = threadIdx.x;
    const int bd = t >> 7;              // 0..7
    const int l  = t & 127;
    const unsigned int* base = pmin + (size_t)bd * NPTS;
    float sum = 0.f, mx = -1.f;
    #pragma unroll
    for (int i = 0; i < NPTS / 128; ++i) {
        const float f = __uint_as_float(base[i * 128 + l]);
        sum += f;
        mx = fmaxf(mx, f);
    }
    // threads of one bd occupy exactly waves 2bd, 2bd+1 -> per-wave reduce.
    #pragma unroll
    for (int off = 32; off; off >>= 1) {
        sum += __shfl_down(sum, off, 64);
        mx = fmaxf(mx, __shfl_down(mx, off, 64));
    }
    __shared__ float ss[16], sm[16];
    if ((t & 63) == 0) { ss[t >> 6] = sum; sm[t >> 6] = mx; }
    __syncthreads();
    if (t == 0) {
        float acc = 0.f;
        #pragma unroll
        for (int d = 0; d < 8; ++d) {
            const float S = ss[2 * d] + ss[2 * d + 1];
            const float M = fmaxf(sm[2 * d], sm[2 * d + 1]);
            // even bd (pred2gt): mean + max ; odd bd (gt2pred): mean only.
            acc += S * (1.f / NPTS) + ((d & 1) ? 0.f : M);
        }
        out[0] = acc * (1.f / BATCH);
    }
}

extern "C" void kernel_launch(void* const* d_in, const int* in_sizes, int n_in,
                              void* d_out, int out_size, void* d_ws, size_t ws_size,
                              hipStream_t stream) {
    const float* pred = (const float*)d_in[0];
    const float* gt   = (const float*)d_in[1];

    unsigned int* pmin = (unsigned int*)d_ws;   // 2*B*NPTS uints = 256 KB

    hipMemsetAsync(pmin, 0xFF, (size_t)2 * BATCH * NPTS * 4, stream);  // +inf sentinel

    dim3 g1(NCHUNKS, SLICES, 2 * BATCH);   // 2 x 64 x 8 = 1024 blocks (4/CU)
    nn_fused<<<g1, TPB, 0, stream>>>(pred, gt, pmin);
    reduce_all<<<dim3(1), 1024, 0, stream>>>(pmin, (float*)d_out);
}

// Round 6
// 101.449 us; speedup vs baseline: 1.0507x; 1.0507x over previous
//
#include <hip/hip_runtime.h>

// ChamferLoss: B=4, N=M=8192, D=3, fp32.
// loss = mean_b[ mean(pred2gt) + mean(gt2pred) + max(pred2gt) ]
// R6: R5's packed fp32 math (v_pk_fma_f32) + R4's memory layout. R5 proved pk
// halves VALU cycles (50us->30us equiv) but its adjacent-point-pair layout
// tripled atomic/write traffic (16->49MB) and 5x'd fetch. Fix: pack points
// k*TPB+t and (k+8)*TPB+t into one v2f -- loads & atomics identical to R4
// (lane-contiguous), only register packing changes. y-splat free via op_sel.

typedef float v2f __attribute__((ext_vector_type(2)));

#define BATCH   4
#define NPTS    8192
#define SLICES  64
#define MS      (NPTS / SLICES)     // 128 y-points per slice
#define NP2     8                   // v2f regs per thread = 16 points
#define TPB     256
#define CHUNK   (TPB * NP2 * 2)     // 4096 x-points per block
#define NCHUNKS (NPTS / CHUNK)      // 2

__global__ __launch_bounds__(TPB, 4)   // cap VGPR <=128: 4 waves/SIMD
void nn_fused(const float* __restrict__ pred,
              const float* __restrict__ gt,
              unsigned int* __restrict__ pmin) {
    const int c  = blockIdx.x;       // x chunk
    const int s  = blockIdx.y;       // y slice
    const int bd = blockIdx.z;       // b*2 + dir
    const int b  = bd >> 1;
    const int dir = bd & 1;
    const float* x = (dir ? gt : pred) + (size_t)b * NPTS * 3;
    const float* y = (dir ? pred : gt) + (size_t)b * NPTS * 3;

    __shared__ float4 ys[MS];        // {yx, yy, yz, y2}  (2 KB)
    const int t = threadIdx.x;
    if (t < MS) {
        const float yx = y[(s * MS + t) * 3 + 0];
        const float yy = y[(s * MS + t) * 3 + 1];
        const float yz = y[(s * MS + t) * 3 + 2];
        ys[t] = make_float4(yx, yy, yz, yx * yx + yy * yy + yz * yz);
    }
    __syncthreads();

    // e_j = y2 + (-2x).y ; d = x2 + min_j e_j (x2 hoisted out of j-loop).
    // v2f halves hold point k (lo) and point k+NP2 (hi) -- R4's addressing.
    v2f px[NP2], py[NP2], pz[NP2], x2[NP2], emin[NP2];
    #pragma unroll
    for (int k = 0; k < NP2; ++k) {
        const int pa = c * CHUNK + k * TPB + t;          // lo point
        const int pb = pa + NP2 * TPB;                   // hi point
        const float ax = x[pa * 3 + 0], ay = x[pa * 3 + 1], az = x[pa * 3 + 2];
        const float bx = x[pb * 3 + 0], by = x[pb * 3 + 1], bz = x[pb * 3 + 2];
        x2[k] = (v2f){ax * ax + ay * ay + az * az, bx * bx + by * by + bz * bz};
        px[k] = (v2f){-2.f * ax, -2.f * bx};
        py[k] = (v2f){-2.f * ay, -2.f * by};
        pz[k] = (v2f){-2.f * az, -2.f * bz};
        emin[k] = (v2f){3.4e38f, 3.4e38f};
    }

    // Per 2-y iter per thread: 48 v_pk_fma_f32 + 16 v_pk_min_f32 vs
    // 2 ds_read_b128. y-splats are op_sel broadcasts (free).
    for (int j = 0; j < MS; j += 2) {
        const float4 q0 = ys[j];
        const float4 q1 = ys[j + 1];
        const v2f q0x = {q0.x, q0.x}, q0y = {q0.y, q0.y}, q0z = {q0.z, q0.z}, q0w = {q0.w, q0.w};
        const v2f q1x = {q1.x, q1.x}, q1y = {q1.y, q1.y}, q1z = {q1.z, q1.z}, q1w = {q1.w, q1.w};
        #pragma unroll
        for (int k = 0; k < NP2; ++k) {
            v2f e0 = __builtin_elementwise_fma(pz[k], q0z,
                     __builtin_elementwise_fma(py[k], q0y,
                     __builtin_elementwise_fma(px[k], q0x, q0w)));
            v2f e1 = __builtin_elementwise_fma(pz[k], q1z,
                     __builtin_elementwise_fma(py[k], q1y,
                     __builtin_elementwise_fma(px[k], q1x, q1w)));
            emin[k] = __builtin_elementwise_min(emin[k],
                      __builtin_elementwise_min(e0, e1));
        }
    }

    // Atomic epilogue: same addresses as R4 (lane-contiguous per k).
    unsigned int* o = pmin + (size_t)bd * NPTS + c * CHUNK;
    #pragma unroll
    for (int k = 0; k < NP2; ++k) {
        v2f d = emin[k] + x2[k];
        d = __builtin_elementwise_max(d, (v2f){0.f, 0.f});   // sqdist >= 0
        atomicMin(&o[k * TPB + t],             __float_as_uint(d.x));
        atomicMin(&o[(k + NP2) * TPB + t],     __float_as_uint(d.y));
    }
}

// One 1024-thread block: 128 threads per bd; sum + max per bd; write out[0].
__global__ __launch_bounds__(1024)
void reduce_all(const unsigned int* __restrict__ pmin,
                float* __restrict__ out) {
    const int t  = threadIdx.x;
    const int bd = t >> 7;              // 0..7
    const int l  = t & 127;
    const unsigned int* base = pmin + (size_t)bd * NPTS;
    float sum = 0.f, mx = -1.f;
    #pragma unroll
    for (int i = 0; i < NPTS / 128; ++i) {
        const float f = __uint_as_float(base[i * 128 + l]);
        sum += f;
        mx = fmaxf(mx, f);
    }
    // threads of one bd occupy exactly waves 2bd, 2bd+1 -> per-wave reduce.
    #pragma unroll
    for (int off = 32; off; off >>= 1) {
        sum += __shfl_down(sum, off, 64);
        mx = fmaxf(mx, __shfl_down(mx, off, 64));
    }
    __shared__ float ss[16], sm[16];
    if ((t & 63) == 0) { ss[t >> 6] = sum; sm[t >> 6] = mx; }
    __syncthreads();
    if (t == 0) {
        float acc = 0.f;
        #pragma unroll
        for (int d = 0; d < 8; ++d) {
            const float S = ss[2 * d] + ss[2 * d + 1];
            const float M = fmaxf(sm[2 * d], sm[2 * d + 1]);
            // even bd (pred2gt): mean + max ; odd bd (gt2pred): mean only.
            acc += S * (1.f / NPTS) + ((d & 1) ? 0.f : M);
        }
        out[0] = acc * (1.f / BATCH);
    }
}

extern "C" void kernel_launch(void* const* d_in, const int* in_sizes, int n_in,
                              void* d_out, int out_size, void* d_ws, size_t ws_size,
                              hipStream_t stream) {
    const float* pred = (const float*)d_in[0];
    const float* gt   = (const float*)d_in[1];

    unsigned int* pmin = (unsigned int*)d_ws;   // 2*B*NPTS uints = 256 KB

    hipMemsetAsync(pmin, 0xFF, (size_t)2 * BATCH * NPTS * 4, stream);  // +inf sentinel

    dim3 g1(NCHUNKS, SLICES, 2 * BATCH);   // 2 x 64 x 8 = 1024 blocks (4/CU)
    nn_fused<<<g1, TPB, 0, stream>>>(pred, gt, pmin);
    reduce_all<<<dim3(1), 1024, 0, stream>>>(pmin, (float*)d_out);
}